// Round 10
// baseline (262.289 us; speedup 1.0000x reference)
//
#include <hip/hip_runtime.h>
#include <math.h>

#define HH 512
#define WW 512
#define BB 32
#define CHUNK 16

__device__ __forceinline__ float min3f(float a, float b, float c) {
    return fminf(fminf(a, b), c);
}
__device__ __forceinline__ float max3f(float a, float b, float c) {
    return fmaxf(fmaxf(a, b), c);
}

// Unconditional clamped row load (row index clamp is wave-uniform SALU,
// column bases pre-clamped loop-invariant). Duplicating an in-window value
// never changes a min; the only pad elements feeding non-masked min-pool
// outputs are xr[3] (lane s==0) and xr[8] (lane s==127) -> clamp to xr[0]/xr[7].
__device__ __forceinline__ void loadrowC(const float* __restrict__ img, int R,
                                         int cm4, int c0, int cp4,
                                         bool isL, bool isR, float* xr) {
    const int Rc = R < 0 ? 0 : (R > HH - 1 ? HH - 1 : R);   // wave-uniform
    const float* rb = img + (size_t)Rc * WW;
    float4 v0 = *(const float4*)(rb + cm4);
    float4 v1 = *(const float4*)(rb + c0);
    float4 v2 = *(const float4*)(rb + cp4);
    xr[0] = v0.x; xr[1] = v0.y; xr[2] = v0.z; xr[3] = v0.w;
    xr[4] = v1.x; xr[5] = v1.y; xr[6] = v1.z; xr[7] = v1.w;
    xr[8] = v2.x; xr[9] = v2.y; xr[10] = v2.z; xr[11] = v2.w;
    if (isL) xr[3] = xr[0];
    if (isR) xr[8] = xr[7];
}

// ONE soft-skeletonize iteration per pass (T=1), register-pipelined, no LDS.
// Rationale (round 9): replay dispatches with FETCH~0 ran at identical speed
// -> pure latency/issue-bound. T=2's ~150-float live state locks VGPR into
// the (128,256] bucket (2 waves/SIMD). T=1 state fits <=128 VGPR ->
// __launch_bounds__(256,4) -> 4 waves/SIMD, and deletes halo recompute
// (~50 inst/row vs ~120). Memory passes double but are L3-resident.
// Pipeline: load x(R) -> hm(R) -> mn(R-1) -> hx(R-1) -> out(R-2); lag 2,
// 4 warm-up rows, walk CHUNK+4 rows.
// FUSED=1: final pass accumulates acc0=sum(out*companion), acc1=sum(out).
template <int FUSED>
__global__ __launch_bounds__(256, 4) void skel1r_t(const float* __restrict__ srcA,
                                                   const float* __restrict__ srcB,
                                                   const float* __restrict__ cmpA,
                                                   const float* __restrict__ cmpB,
                                                   float* __restrict__ dst,
                                                   float* __restrict__ partials) {
    const int s = blockIdx.x * 64 + threadIdx.x;            // span 0..127
    const int y0 = (blockIdx.y * 4 + threadIdx.y) * CHUNK;  // output row start
    const int z = blockIdx.z;
    const float* img = (z < BB) ? (srcA + (size_t)z * (HH * WW))
                                : (srcB + (size_t)(z - BB) * (HH * WW));
    const float* cmp = nullptr;
    if (FUSED) cmp = (z < BB) ? (cmpA + (size_t)z * (HH * WW))
                              : (cmpB + (size_t)(z - BB) * (HH * WW));
    float* outp = FUSED ? nullptr : (dst + (size_t)z * (HH * WW));
    const int gx0 = 4 * s;
    const bool isL = (s == 0), isR = (s == 127);
    const int cm4 = isL ? 0 : gx0 - 4;      // clamped left-load base
    const int cp4 = isR ? gx0 : gx0 + 4;    // clamped right-load base

    // ring state: hm rows R-2,R-1 (6-wide); hx rows R-3,R-2 (4-wide);
    // mn(R-2) at output cols (4); x rows R-2,R-1 at output cols (4+4)
    float hma[6], hmb[6];
    float hxa[4], hxb[4], mnp[4];
    float x0a[4], x0b[4];
    #pragma unroll
    for (int c = 0; c < 6; ++c) { hma[c] = INFINITY; hmb[c] = INFINITY; }
    #pragma unroll
    for (int m = 0; m < 4; ++m) { hxa[m] = -INFINITY; hxb[m] = -INFINITY; mnp[m] = -INFINITY; x0a[m] = INFINITY; x0b[m] = INFINITY; }

    float acc0 = 0.0f, acc1 = 0.0f;

    // depth-3 prefetch: xA = row R, xB = R+1, xC = R+2, xD loaded for R+3
    float xA[12], xB[12], xC[12];
    loadrowC(img, y0 - 2, cm4, gx0, cp4, isL, isR, xA);
    loadrowC(img, y0 - 1, cm4, gx0, cp4, isL, isR, xB);
    loadrowC(img, y0,     cm4, gx0, cp4, isL, isR, xC);
    // depth-3 companion ring (FUSED): loaded at rr for consumption at rr+3
    float4 cmpQ0, cmpQ1, cmpQ2;
    cmpQ0.x = cmpQ0.y = cmpQ0.z = cmpQ0.w = 0.f;
    cmpQ1 = cmpQ0; cmpQ2 = cmpQ0;

    #pragma unroll
    for (int rr = 0; rr < CHUNK + 4; ++rr) {
        const int R = y0 - 2 + rr;

        float xD[12];
        if (rr < CHUNK + 1) {
            loadrowC(img, R + 3, cm4, gx0, cp4, isL, isR, xD);
        } else {
            #pragma unroll
            for (int i = 0; i < 12; ++i) xD[i] = INFINITY;  // dead, DCE'd
        }

        float4 cmpCur;
        if (FUSED) {
            cmpCur = cmpQ0;
            cmpQ0 = cmpQ1; cmpQ1 = cmpQ2;                    // free after unroll
            if (rr >= 1 && rr < CHUNK + 1) {
                // out row consumed 3 iterations later: y0-4+(rr+3) = y0-1+rr
                cmpQ2 = *(const float4*)(cmp + (size_t)(y0 - 1 + rr) * WW + gx0);
            }
        }

        // ---- horizontal min, row R (hm[c] = col gx0-1+c, c=0..5) ----
        float hmc[6];
        #pragma unroll
        for (int c = 0; c < 6; ++c) hmc[c] = min3f(xA[2 + c], xA[3 + c], xA[4 + c]);

        // ---- min-pool row R-1 (cols gx0-1..gx0+4) ----
        float mnn[6];
        #pragma unroll
        for (int c = 0; c < 6; ++c) mnn[c] = min3f(hma[c], hmb[c], hmc[c]);
        if (!((unsigned)(R - 1) < HH)) {        // wave-uniform, rarely taken
            #pragma unroll
            for (int c = 0; c < 6; ++c) mnn[c] = -INFINITY;
        }
        if (isL) mnn[0] = -INFINITY;            // col -1
        if (isR) mnn[5] = -INFINITY;            // col 512

        // ---- horiz max of mn, row R-1 (hx[m] = col gx0+m) ----
        float hxn[4];
        #pragma unroll
        for (int m = 0; m < 4; ++m) hxn[m] = max3f(mnn[m], mnn[m + 1], mnn[m + 2]);

        // ---- update: out row R-2 = relu(x - relu(maxpool(mn) - mn)) ----
        if (rr >= 4) {
            float o[4];
            #pragma unroll
            for (int m = 0; m < 4; ++m) {
                float mp = max3f(hxa[m], hxb[m], hxn[m]);
                float ct = fmaxf(mp - mnp[m], 0.0f);
                o[m] = fmaxf(x0a[m] - ct, 0.0f);
            }
            if (FUSED) {
                acc0 += o[0] * cmpCur.x + o[1] * cmpCur.y + o[2] * cmpCur.z + o[3] * cmpCur.w;
                acc1 += o[0] + o[1] + o[2] + o[3];
            } else {
                float4 ov;
                ov.x = o[0]; ov.y = o[1]; ov.z = o[2]; ov.w = o[3];
                *(float4*)(outp + (size_t)(R - 2) * WW + gx0) = ov;
            }
        }

        // ---- ring shifts (free after full unroll) ----
        #pragma unroll
        for (int c = 0; c < 6; ++c) { hma[c] = hmb[c]; hmb[c] = hmc[c]; }
        #pragma unroll
        for (int m = 0; m < 4; ++m) {
            mnp[m] = mnn[m + 1];
            hxa[m] = hxb[m]; hxb[m] = hxn[m];
            x0a[m] = x0b[m]; x0b[m] = xA[4 + m];
        }
        #pragma unroll
        for (int i = 0; i < 12; ++i) { xA[i] = xB[i]; xB[i] = xC[i]; xC[i] = xD[i]; }
    }

    if (FUSED) {
        for (int off = 32; off; off >>= 1) {
            acc0 += __shfl_down(acc0, off);
            acc1 += __shfl_down(acc1, off);
        }
        __shared__ float red[4][2];
        if (threadIdx.x == 0) { red[threadIdx.y][0] = acc0; red[threadIdx.y][1] = acc1; }
        __syncthreads();
        if (threadIdx.x == 0 && threadIdx.y == 0) {
            const int tile = blockIdx.x * gridDim.y + blockIdx.y;  // 0..15
            float* p = partials + ((size_t)z * 16 + tile) * 2;
            p[0] = red[0][0] + red[1][0] + red[2][0] + red[3][0];
            p[1] = red[0][1] + red[1][1] + red[2][1] + red[3][1];
        }
    }
}

// partials layout: [z][16 tile slots][2];
// z<32: (sum clp*tgt, sum clp); z>=32: (sum skt*prd, sum skt)
__global__ __launch_bounds__(64) void finalize2(const float* __restrict__ partials,
                                                int ntiles,
                                                float* __restrict__ out) {
    const int b = threadIdx.x;
    float iflat = 0.f, tflat = 0.f;
    if (b < BB) {
        float v0 = 0.f, v1 = 0.f, v2 = 0.f, v3 = 0.f;
        for (int t = 0; t < ntiles; ++t) {
            v0 += partials[((size_t)b * 16 + t) * 2 + 0];
            v1 += partials[((size_t)b * 16 + t) * 2 + 1];
            v2 += partials[((size_t)(b + BB) * 16 + t) * 2 + 0];
            v3 += partials[((size_t)(b + BB) * 16 + t) * 2 + 1];
        }
        iflat = (v0 + 1e-6f) / (v1 + 1e-6f);
        tflat = (v2 + 1e-6f) / (v3 + 1e-6f);
    }
    float prod = iflat * tflat;
    float ssum = iflat + tflat;
    for (int off = 32; off; off >>= 1) {
        prod += __shfl_down(prod, off);
        ssum += __shfl_down(ssum, off);
    }
    if (threadIdx.x == 0) out[0] = 1.0f - 2.0f * prod / ssum;
}

extern "C" void kernel_launch(void* const* d_in, const int* in_sizes, int n_in,
                              void* d_out, int out_size, void* d_ws, size_t ws_size,
                              hipStream_t stream) {
    const float* pred = (const float*)d_in[0];
    const float* target = (const float*)d_in[1];
    float* out = (float*)d_out;
    char* ws = (char*)d_ws;
    const size_t N = (size_t)HH * WW;
    const size_t HALF = (size_t)BB * N;                 // 32 imgs of floats
    const size_t IMG32 = HALF * sizeof(float);          // 32 MB

    dim3 block(64, 4);
    const int nby = HH / (CHUNK * 4);                   // 8
    const int ntiles = 2 * nby;                         // 16

    if (ws_size >= 4 * IMG32 + (1 << 16)) {
        // z=64 path: both chains per dispatch; 10 passes ping-pong A<->B
        float* A = (float*)ws;
        float* B = (float*)(ws + 2 * IMG32);
        float* partials = (float*)(ws + 4 * IMG32);     // 64*16*2 floats
        dim3 grid(2, nby, 2 * BB);
        skel1r_t<0><<<grid, block, 0, stream>>>(pred, target, nullptr, nullptr, A, nullptr);   // 1
        skel1r_t<0><<<grid, block, 0, stream>>>(A, A + HALF, nullptr, nullptr, B, nullptr);    // 2
        skel1r_t<0><<<grid, block, 0, stream>>>(B, B + HALF, nullptr, nullptr, A, nullptr);    // 3
        skel1r_t<0><<<grid, block, 0, stream>>>(A, A + HALF, nullptr, nullptr, B, nullptr);    // 4
        skel1r_t<0><<<grid, block, 0, stream>>>(B, B + HALF, nullptr, nullptr, A, nullptr);    // 5
        skel1r_t<0><<<grid, block, 0, stream>>>(A, A + HALF, nullptr, nullptr, B, nullptr);    // 6
        skel1r_t<0><<<grid, block, 0, stream>>>(B, B + HALF, nullptr, nullptr, A, nullptr);    // 7
        skel1r_t<0><<<grid, block, 0, stream>>>(A, A + HALF, nullptr, nullptr, B, nullptr);    // 8
        skel1r_t<0><<<grid, block, 0, stream>>>(B, B + HALF, nullptr, nullptr, A, nullptr);    // 9
        // pass 10 fused with reduction: z<32 companion=target, z>=32 companion=pred
        skel1r_t<1><<<grid, block, 0, stream>>>(A, A + HALF, target, pred, nullptr, partials); // 10
        finalize2<<<1, 64, 0, stream>>>(partials, ntiles, out);
    } else {
        // fallback: z=32 path with 2x32MB buffers, 10 passes per chain
        float* b0 = (float*)ws;
        float* b1 = (float*)(ws + IMG32);
        float* partials = (float*)(ws + 2 * IMG32);
        dim3 grid(2, nby, BB);
        // pred chain: ends in b0 after 9 passes, fused 10th
        skel1r_t<0><<<grid, block, 0, stream>>>(pred, pred, nullptr, nullptr, b0, nullptr);
        for (int i = 1; i < 9; ++i) {
            if (i & 1) skel1r_t<0><<<grid, block, 0, stream>>>(b0, b0, nullptr, nullptr, b1, nullptr);
            else       skel1r_t<0><<<grid, block, 0, stream>>>(b1, b1, nullptr, nullptr, b0, nullptr);
        }
        skel1r_t<1><<<grid, block, 0, stream>>>(b0, b0, target, target, nullptr, partials);
        // target chain
        skel1r_t<0><<<grid, block, 0, stream>>>(target, target, nullptr, nullptr, b0, nullptr);
        for (int i = 1; i < 9; ++i) {
            if (i & 1) skel1r_t<0><<<grid, block, 0, stream>>>(b0, b0, nullptr, nullptr, b1, nullptr);
            else       skel1r_t<0><<<grid, block, 0, stream>>>(b1, b1, nullptr, nullptr, b0, nullptr);
        }
        skel1r_t<1><<<grid, block, 0, stream>>>(b0, b0, pred, pred, nullptr,
                                                partials + (size_t)BB * 16 * 2);
        finalize2<<<1, 64, 0, stream>>>(partials, ntiles, out);
    }
}

// Round 11
// 155.285 us; speedup vs baseline: 1.6891x; 1.6891x over previous
//
#include <hip/hip_runtime.h>
#include <math.h>

#define HH 512
#define WW 512
#define BB 32
#define CHUNK 32

__device__ __forceinline__ float min3f(float a, float b, float c) {
    return fminf(fminf(a, b), c);
}
__device__ __forceinline__ float max3f(float a, float b, float c) {
    return fmaxf(fmaxf(a, b), c);
}
__device__ __forceinline__ float bf2f(unsigned short h) {
    return __uint_as_float((unsigned)h << 16);
}
__device__ __forceinline__ unsigned short f2bf(float f) {
    unsigned u = __float_as_uint(f);
    u += 0x7FFF + ((u >> 16) & 1);          // RNE; inputs are finite in [0,1]
    return (unsigned short)(u >> 16);
}

// Clamped 12-element row load (cols gx0-4..gx0+7), f32 or bf16 source.
// Row clamp is wave-uniform SALU; column bases pre-clamped loop-invariant.
// Duplicating an in-window value never changes a min; only pad elements
// feeding non-masked min-pool outputs are xr[3] (lane s==0) and xr[8]
// (lane s==127) -> clamp to xr[0]/xr[7].
template <int F32>
__device__ __forceinline__ void loadrow12(const float* __restrict__ imgF,
                                          const unsigned short* __restrict__ imgH,
                                          int R, int cm4, int c0, int cp4,
                                          bool isL, bool isR, float* xr) {
    const int Rc = R < 0 ? 0 : (R > HH - 1 ? HH - 1 : R);   // wave-uniform
    if (F32) {
        const float* rb = imgF + (size_t)Rc * WW;
        float4 v0 = *(const float4*)(rb + cm4);
        float4 v1 = *(const float4*)(rb + c0);
        float4 v2 = *(const float4*)(rb + cp4);
        xr[0] = v0.x; xr[1] = v0.y; xr[2] = v0.z; xr[3] = v0.w;
        xr[4] = v1.x; xr[5] = v1.y; xr[6] = v1.z; xr[7] = v1.w;
        xr[8] = v2.x; xr[9] = v2.y; xr[10] = v2.z; xr[11] = v2.w;
    } else {
        const unsigned short* rb = imgH + (size_t)Rc * WW;
        ushort4 v0 = *(const ushort4*)(rb + cm4);
        ushort4 v1 = *(const ushort4*)(rb + c0);
        ushort4 v2 = *(const ushort4*)(rb + cp4);
        xr[0] = bf2f(v0.x); xr[1] = bf2f(v0.y); xr[2] = bf2f(v0.z); xr[3] = bf2f(v0.w);
        xr[4] = bf2f(v1.x); xr[5] = bf2f(v1.y); xr[6] = bf2f(v1.z); xr[7] = bf2f(v1.w);
        xr[8] = bf2f(v2.x); xr[9] = bf2f(v2.y); xr[10] = bf2f(v2.z); xr[11] = bf2f(v2.w);
    }
    if (isL) xr[3] = xr[0];
    if (isR) xr[8] = xr[7];
}

// Two fused soft-skeletonize iterations (T=2), register-pipelined, no LDS,
// fully unrolled 40-row walk, depth-3 prefetch, clamped loads.
// Round-10 lesson: the chain is TOTAL-TRAFFIC bound (~21us/pass floor for
// 128MB at ~6TB/s L3-effective). Intermediates stored as bf16: halves the
// per-pass bytes. Precision: target chain is exact in bf16 ({0,1} closed
// under min/max/relu); pred chain takes <=4 RNE round-trips (~2e-3 rel).
// SRCF32=1: pass 1 (f32 inputs). FUSED=1: final pass accumulates
// acc0=sum(out*companion_f32), acc1=sum(out); no store.
template <int SRCF32, int FUSED>
__global__ __launch_bounds__(256) void skel2b_t(const float* __restrict__ sfA,
                                                const float* __restrict__ sfB,
                                                const unsigned short* __restrict__ shA,
                                                const unsigned short* __restrict__ shB,
                                                const float* __restrict__ cmpA,
                                                const float* __restrict__ cmpB,
                                                unsigned short* __restrict__ dst,
                                                float* __restrict__ partials) {
    const int s = blockIdx.x * 64 + threadIdx.x;            // span 0..127
    const int y0 = (blockIdx.y * 4 + threadIdx.y) * CHUNK;  // output row start
    const int z = blockIdx.z;
    const float* imgF = nullptr;
    const unsigned short* imgH = nullptr;
    if (SRCF32) imgF = (z < BB) ? (sfA + (size_t)z * (HH * WW))
                                : (sfB + (size_t)(z - BB) * (HH * WW));
    else        imgH = (z < BB) ? (shA + (size_t)z * (HH * WW))
                                : (shB + (size_t)(z - BB) * (HH * WW));
    const float* cmp = nullptr;
    if (FUSED) cmp = (z < BB) ? (cmpA + (size_t)z * (HH * WW))
                              : (cmpB + (size_t)(z - BB) * (HH * WW));
    unsigned short* outp = FUSED ? nullptr : (dst + (size_t)z * (HH * WW));
    const int gx0 = 4 * s;
    const bool isL = (s == 0), isR = (s == 127);
    const int cm4 = isL ? 0 : gx0 - 4;      // clamped left-load base
    const int cp4 = isR ? gx0 : gx0 + 4;    // clamped right-load base

    // ring state (fully unrolled loop -> pure register renaming)
    float hm0a[10], hm0b[10], mn0p[8];
    float hx0a[8], hx0b[8];
    float x0a[8], x0b[8];
    float hm1a[6], hm1b[6], mn1p[4];
    float hx1a[4], hx1b[4];
    float x1a[4], x1b[4];

    #pragma unroll
    for (int i = 0; i < 10; ++i) { hm0a[i] = INFINITY; hm0b[i] = INFINITY; }
    #pragma unroll
    for (int j = 0; j < 8; ++j)  { mn0p[j] = -INFINITY; hx0a[j] = -INFINITY; hx0b[j] = -INFINITY; x0a[j] = INFINITY; x0b[j] = INFINITY; }
    #pragma unroll
    for (int k = 0; k < 6; ++k)  { hm1a[k] = INFINITY; hm1b[k] = INFINITY; }
    #pragma unroll
    for (int m = 0; m < 4; ++m)  { mn1p[m] = -INFINITY; hx1a[m] = -INFINITY; hx1b[m] = -INFINITY; x1a[m] = INFINITY; x1b[m] = INFINITY; }

    float acc0 = 0.0f, acc1 = 0.0f;

    // depth-3 prefetch: xA = row R, xB = R+1, xC = R+2, xD loaded for R+3
    float xA[12], xB[12], xC[12];
    loadrow12<SRCF32>(imgF, imgH, y0 - 4, cm4, gx0, cp4, isL, isR, xA);
    loadrow12<SRCF32>(imgF, imgH, y0 - 3, cm4, gx0, cp4, isL, isR, xB);
    loadrow12<SRCF32>(imgF, imgH, y0 - 2, cm4, gx0, cp4, isL, isR, xC);
    // depth-3 companion ring: loaded at rr for consumption at rr+3
    float4 cmpQ0, cmpQ1, cmpQ2;
    cmpQ0.x = cmpQ0.y = cmpQ0.z = cmpQ0.w = 0.f;
    cmpQ1 = cmpQ0; cmpQ2 = cmpQ0;

    #pragma unroll
    for (int rr = 0; rr < CHUNK + 8; ++rr) {
        const int R = y0 - 4 + rr;

        float xD[12];
        if (rr < CHUNK + 5) {
            loadrow12<SRCF32>(imgF, imgH, R + 3, cm4, gx0, cp4, isL, isR, xD);
        } else {
            #pragma unroll
            for (int i = 0; i < 12; ++i) xD[i] = INFINITY;  // dead, DCE'd
        }

        float4 cmpCur;
        if (FUSED) {
            cmpCur = cmpQ0;
            cmpQ0 = cmpQ1; cmpQ1 = cmpQ2;                    // free after unroll
            if (rr >= 5 && rr < CHUNK + 5) {
                // row (R-1) = output row consumed 3 iterations later (in-range)
                cmpQ2 = *(const float4*)(cmp + (size_t)(R - 1) * WW + gx0);
            }
        }

        // ---- iter1 horizontal min, row R ----
        float hm0c[10];
        #pragma unroll
        for (int i = 0; i < 10; ++i) hm0c[i] = min3f(xA[i], xA[i + 1], xA[i + 2]);

        // ---- iter1 min-pool row R-1 ----
        float mn0n[10];
        #pragma unroll
        for (int i = 0; i < 10; ++i) mn0n[i] = min3f(hm0a[i], hm0b[i], hm0c[i]);
        if (!((unsigned)(R - 1) < HH)) {        // wave-uniform, rarely taken
            #pragma unroll
            for (int i = 0; i < 10; ++i) mn0n[i] = -INFINITY;
        }
        if (isL) { mn0n[0] = -INFINITY; mn0n[1] = -INFINITY; mn0n[2] = -INFINITY; }
        if (isR) { mn0n[7] = -INFINITY; mn0n[8] = -INFINITY; mn0n[9] = -INFINITY; }

        // ---- horiz max of mn0 row R-1 ----
        float hx0n[8];
        #pragma unroll
        for (int j = 0; j < 8; ++j) hx0n[j] = max3f(mn0n[j], mn0n[j + 1], mn0n[j + 2]);

        // ---- iter1 update: x1 row R-2 ----
        float x1n[8];
        #pragma unroll
        for (int j = 0; j < 8; ++j) {
            float mp = max3f(hx0a[j], hx0b[j], hx0n[j]);
            float ct = fmaxf(mp - mn0p[j], 0.0f);
            x1n[j] = fmaxf(x0a[j] - ct, 0.0f);
        }
        if (!((unsigned)(R - 2) < HH)) {
            #pragma unroll
            for (int j = 0; j < 8; ++j) x1n[j] = INFINITY;
        }
        if (isL) { x1n[0] = INFINITY; x1n[1] = INFINITY; }
        if (isR) { x1n[6] = INFINITY; x1n[7] = INFINITY; }

        // ---- iter2 horizontal min, row R-2 ----
        float hm1n[6];
        #pragma unroll
        for (int k = 0; k < 6; ++k) hm1n[k] = min3f(x1n[k], x1n[k + 1], x1n[k + 2]);

        // ---- iter2 min-pool row R-3 ----
        float mn1n[6];
        #pragma unroll
        for (int k = 0; k < 6; ++k) mn1n[k] = min3f(hm1a[k], hm1b[k], hm1n[k]);
        if (!((unsigned)(R - 3) < HH)) {
            #pragma unroll
            for (int k = 0; k < 6; ++k) mn1n[k] = -INFINITY;
        }
        if (isL) mn1n[0] = -INFINITY;
        if (isR) mn1n[5] = -INFINITY;

        // ---- horiz max of mn1 row R-3 ----
        float hx1n[4];
        #pragma unroll
        for (int m = 0; m < 4; ++m) hx1n[m] = max3f(mn1n[m], mn1n[m + 1], mn1n[m + 2]);

        // ---- iter2 update: x2 row R-4 ----
        if (rr >= 8) {
            float o[4];
            #pragma unroll
            for (int m = 0; m < 4; ++m) {
                float mp = max3f(hx1a[m], hx1b[m], hx1n[m]);
                float ct = fmaxf(mp - mn1p[m], 0.0f);
                o[m] = fmaxf(x1a[m] - ct, 0.0f);
            }
            if (FUSED) {
                acc0 += o[0] * cmpCur.x + o[1] * cmpCur.y + o[2] * cmpCur.z + o[3] * cmpCur.w;
                acc1 += o[0] + o[1] + o[2] + o[3];
            } else {
                ushort4 ov;
                ov.x = f2bf(o[0]); ov.y = f2bf(o[1]); ov.z = f2bf(o[2]); ov.w = f2bf(o[3]);
                *(ushort4*)(outp + (size_t)(R - 4) * WW + gx0) = ov;
            }
        }

        // ---- ring shifts (free after full unroll) ----
        #pragma unroll
        for (int i = 0; i < 10; ++i) { hm0a[i] = hm0b[i]; hm0b[i] = hm0c[i]; }
        #pragma unroll
        for (int j = 0; j < 8; ++j)  { mn0p[j] = mn0n[j + 1]; hx0a[j] = hx0b[j]; hx0b[j] = hx0n[j]; x0a[j] = x0b[j]; x0b[j] = xA[j + 2]; }
        #pragma unroll
        for (int k = 0; k < 6; ++k)  { hm1a[k] = hm1b[k]; hm1b[k] = hm1n[k]; }
        #pragma unroll
        for (int m = 0; m < 4; ++m)  { mn1p[m] = mn1n[m + 1]; hx1a[m] = hx1b[m]; hx1b[m] = hx1n[m]; x1a[m] = x1b[m]; x1b[m] = x1n[m + 2]; }
        #pragma unroll
        for (int i = 0; i < 12; ++i) { xA[i] = xB[i]; xB[i] = xC[i]; xC[i] = xD[i]; }
    }

    if (FUSED) {
        for (int off = 32; off; off >>= 1) {
            acc0 += __shfl_down(acc0, off);
            acc1 += __shfl_down(acc1, off);
        }
        __shared__ float red[4][2];
        if (threadIdx.x == 0) { red[threadIdx.y][0] = acc0; red[threadIdx.y][1] = acc1; }
        __syncthreads();
        if (threadIdx.x == 0 && threadIdx.y == 0) {
            const int tile = blockIdx.x * gridDim.y + blockIdx.y;  // 0..7
            float* p = partials + ((size_t)z * 16 + tile) * 2;
            p[0] = red[0][0] + red[1][0] + red[2][0] + red[3][0];
            p[1] = red[0][1] + red[1][1] + red[2][1] + red[3][1];
        }
    }
}

// partials layout: [z][16 tile slots][2] (first ntiles used per z);
// z<32: (sum clp*tgt, sum clp); z>=32: (sum skt*prd, sum skt)
__global__ __launch_bounds__(64) void finalize2(const float* __restrict__ partials,
                                                int ntiles,
                                                float* __restrict__ out) {
    const int b = threadIdx.x;
    float iflat = 0.f, tflat = 0.f;
    if (b < BB) {
        float v0 = 0.f, v1 = 0.f, v2 = 0.f, v3 = 0.f;
        for (int t = 0; t < ntiles; ++t) {
            v0 += partials[((size_t)b * 16 + t) * 2 + 0];
            v1 += partials[((size_t)b * 16 + t) * 2 + 1];
            v2 += partials[((size_t)(b + BB) * 16 + t) * 2 + 0];
            v3 += partials[((size_t)(b + BB) * 16 + t) * 2 + 1];
        }
        iflat = (v0 + 1e-6f) / (v1 + 1e-6f);
        tflat = (v2 + 1e-6f) / (v3 + 1e-6f);
    }
    float prod = iflat * tflat;
    float ssum = iflat + tflat;
    for (int off = 32; off; off >>= 1) {
        prod += __shfl_down(prod, off);
        ssum += __shfl_down(ssum, off);
    }
    if (threadIdx.x == 0) out[0] = 1.0f - 2.0f * prod / ssum;
}

extern "C" void kernel_launch(void* const* d_in, const int* in_sizes, int n_in,
                              void* d_out, int out_size, void* d_ws, size_t ws_size,
                              hipStream_t stream) {
    const float* pred = (const float*)d_in[0];
    const float* target = (const float*)d_in[1];
    float* out = (float*)d_out;
    char* ws = (char*)d_ws;
    const size_t N = (size_t)HH * WW;
    const size_t HALF = (size_t)BB * N;                 // elements per 32-image half
    const size_t IMG16 = HALF * sizeof(unsigned short); // 16 MB (bf16, 32 imgs)

    dim3 block(64, 4);
    const int nby = HH / (CHUNK * 4);                   // 4
    const int ntiles = 2 * nby;                         // 8

    if (ws_size >= 4 * IMG16 + (1 << 16)) {
        // z=64 path: both chains per dispatch; bf16 ping-pong A<->B (32MB each)
        unsigned short* A = (unsigned short*)ws;
        unsigned short* B = (unsigned short*)(ws + 2 * IMG16);
        float* partials = (float*)(ws + 4 * IMG16);     // 64*16*2 floats
        dim3 grid(2, nby, 2 * BB);
        skel2b_t<1, 0><<<grid, block, 0, stream>>>(pred, target, nullptr, nullptr,
                                                   nullptr, nullptr, A, nullptr);
        skel2b_t<0, 0><<<grid, block, 0, stream>>>(nullptr, nullptr, A, A + HALF,
                                                   nullptr, nullptr, B, nullptr);
        skel2b_t<0, 0><<<grid, block, 0, stream>>>(nullptr, nullptr, B, B + HALF,
                                                   nullptr, nullptr, A, nullptr);
        skel2b_t<0, 0><<<grid, block, 0, stream>>>(nullptr, nullptr, A, A + HALF,
                                                   nullptr, nullptr, B, nullptr);
        // final pass fused with reduction: z<32 companion=target, z>=32 companion=pred
        skel2b_t<0, 1><<<grid, block, 0, stream>>>(nullptr, nullptr, B, B + HALF,
                                                   target, pred, nullptr, partials);
        finalize2<<<1, 64, 0, stream>>>(partials, ntiles, out);
    } else {
        // fallback: z=32 path with 2x16MB bf16 buffers, per-chain passes
        unsigned short* b0 = (unsigned short*)ws;
        unsigned short* b1 = (unsigned short*)(ws + IMG16);
        float* partials = (float*)(ws + 2 * IMG16);
        dim3 grid(2, nby, BB);
        // pred chain
        skel2b_t<1, 0><<<grid, block, 0, stream>>>(pred, pred, nullptr, nullptr,
                                                   nullptr, nullptr, b0, nullptr);
        skel2b_t<0, 0><<<grid, block, 0, stream>>>(nullptr, nullptr, b0, b0,
                                                   nullptr, nullptr, b1, nullptr);
        skel2b_t<0, 0><<<grid, block, 0, stream>>>(nullptr, nullptr, b1, b1,
                                                   nullptr, nullptr, b0, nullptr);
        skel2b_t<0, 0><<<grid, block, 0, stream>>>(nullptr, nullptr, b0, b0,
                                                   nullptr, nullptr, b1, nullptr);
        skel2b_t<0, 1><<<grid, block, 0, stream>>>(nullptr, nullptr, b1, b1,
                                                   target, target, nullptr, partials);
        // target chain
        skel2b_t<1, 0><<<grid, block, 0, stream>>>(target, target, nullptr, nullptr,
                                                   nullptr, nullptr, b0, nullptr);
        skel2b_t<0, 0><<<grid, block, 0, stream>>>(nullptr, nullptr, b0, b0,
                                                   nullptr, nullptr, b1, nullptr);
        skel2b_t<0, 0><<<grid, block, 0, stream>>>(nullptr, nullptr, b1, b1,
                                                   nullptr, nullptr, b0, nullptr);
        skel2b_t<0, 0><<<grid, block, 0, stream>>>(nullptr, nullptr, b0, b0,
                                                   nullptr, nullptr, b1, nullptr);
        skel2b_t<0, 1><<<grid, block, 0, stream>>>(nullptr, nullptr, b1, b1,
                                                   pred, pred, nullptr,
                                                   partials + (size_t)BB * 16 * 2);
        finalize2<<<1, 64, 0, stream>>>(partials, ntiles, out);
    }
}

// Round 12
// 140.880 us; speedup vs baseline: 1.8618x; 1.1022x over previous
//
#include <hip/hip_runtime.h>
#include <math.h>

#define HH 512
#define WW 512
#define BB 32
#define CHUNK 32

__device__ __forceinline__ float min3f(float a, float b, float c) {
    return fminf(fminf(a, b), c);
}
__device__ __forceinline__ float max3f(float a, float b, float c) {
    return fmaxf(fmaxf(a, b), c);
}
__device__ __forceinline__ float bf2f(unsigned short h) {
    return __uint_as_float((unsigned)h << 16);
}
__device__ __forceinline__ unsigned short f2bf(float f) {
    unsigned u = __float_as_uint(f);
    u += 0x7FFF + ((u >> 16) & 1);          // RNE; inputs are finite in [0,1]
    return (unsigned short)(u >> 16);
}

// Clamped 12-element row load (cols gx0-4..gx0+7), f32 or bf16 source.
// Row clamp wave-uniform SALU; column bases pre-clamped. Duplicating an
// in-window value never changes a min; only pad elements feeding non-masked
// min-pool outputs are xr[3] (lane s==0) / xr[8] (lane s==127).
template <int F32>
__device__ __forceinline__ void loadrow12(const float* __restrict__ imgF,
                                          const unsigned short* __restrict__ imgH,
                                          int R, int cm4, int c0, int cp4,
                                          bool isL, bool isR, float* xr) {
    const int Rc = R < 0 ? 0 : (R > HH - 1 ? HH - 1 : R);   // wave-uniform
    if (F32) {
        const float* rb = imgF + (size_t)Rc * WW;
        float4 v0 = *(const float4*)(rb + cm4);
        float4 v1 = *(const float4*)(rb + c0);
        float4 v2 = *(const float4*)(rb + cp4);
        xr[0] = v0.x; xr[1] = v0.y; xr[2] = v0.z; xr[3] = v0.w;
        xr[4] = v1.x; xr[5] = v1.y; xr[6] = v1.z; xr[7] = v1.w;
        xr[8] = v2.x; xr[9] = v2.y; xr[10] = v2.z; xr[11] = v2.w;
    } else {
        const unsigned short* rb = imgH + (size_t)Rc * WW;
        ushort4 v0 = *(const ushort4*)(rb + cm4);
        ushort4 v1 = *(const ushort4*)(rb + c0);
        ushort4 v2 = *(const ushort4*)(rb + cp4);
        xr[0] = bf2f(v0.x); xr[1] = bf2f(v0.y); xr[2] = bf2f(v0.z); xr[3] = bf2f(v0.w);
        xr[4] = bf2f(v1.x); xr[5] = bf2f(v1.y); xr[6] = bf2f(v1.z); xr[7] = bf2f(v1.w);
        xr[8] = bf2f(v2.x); xr[9] = bf2f(v2.y); xr[10] = bf2f(v2.z); xr[11] = bf2f(v2.w);
    }
    if (isL) xr[3] = xr[0];
    if (isR) xr[8] = xr[7];
}

// One row of the T=2 pipeline. Ring roles passed explicitly so a 4-row loop
// body needs ZERO cross-iteration copies (pairs alternate; load slots rotate
// period 4). All in-body "rotation copies" coalesce in SSA.
// (o = older row of pair, n = newer; new value written into o, caller swaps.)
template <int SRCF32, int FUSED>
__device__ __forceinline__ void rowstep(
    const float* __restrict__ imgF, const unsigned short* __restrict__ imgH,
    const float* __restrict__ cmp, unsigned short* __restrict__ outp,
    float& acc0, float& acc1,
    int R, int cm4, int gx0, int cp4, bool isL, bool isR, bool doStore,
    float (&xA)[12], float (&xL)[12],
    float (&hm0o)[10], float (&hm0n)[10], float (&mn0p)[8],
    float (&hx0o)[8], float (&hx0n)[8],
    float (&x0o)[8], float (&x0n)[8],
    float (&hm1o)[6], float (&hm1n)[6], float (&mn1p)[4],
    float (&hx1o)[4], float (&hx1n)[4],
    float (&x1o)[4], float (&x1n)[4],
    float4& cqC, float4& cqL) {
    // prefetch row R+3 into xL (slot dead since last iteration)
    loadrow12<SRCF32>(imgF, imgH, R + 3, cm4, gx0, cp4, isL, isR, xL);

    float4 cmpCur;
    if (FUSED) {
        cmpCur = cqC;
        int Rc = R - 1;                                     // out-row consumed 3 steps later
        Rc = Rc < 0 ? 0 : (Rc > HH - 1 ? HH - 1 : Rc);      // wave-uniform clamp
        cqL = *(const float4*)(cmp + (size_t)Rc * WW + gx0);
    }

    // ---- iter1 horizontal min, row R ----
    float hm0c[10];
    #pragma unroll
    for (int i = 0; i < 10; ++i) hm0c[i] = min3f(xA[i], xA[i + 1], xA[i + 2]);

    // ---- iter1 min-pool row R-1 ----
    float mn0n[10];
    #pragma unroll
    for (int i = 0; i < 10; ++i) mn0n[i] = min3f(hm0o[i], hm0n[i], hm0c[i]);
    if (!((unsigned)(R - 1) < HH)) {            // wave-uniform, rarely taken
        #pragma unroll
        for (int i = 0; i < 10; ++i) mn0n[i] = -INFINITY;
    }
    if (isL) { mn0n[0] = -INFINITY; mn0n[1] = -INFINITY; mn0n[2] = -INFINITY; }
    if (isR) { mn0n[7] = -INFINITY; mn0n[8] = -INFINITY; mn0n[9] = -INFINITY; }

    // ---- horiz max of mn0 row R-1 ----
    float hx0c[8];
    #pragma unroll
    for (int j = 0; j < 8; ++j) hx0c[j] = max3f(mn0n[j], mn0n[j + 1], mn0n[j + 2]);

    // ---- iter1 update: x1 row R-2 ----
    float x1c[8];
    #pragma unroll
    for (int j = 0; j < 8; ++j) {
        float mp = max3f(hx0o[j], hx0n[j], hx0c[j]);
        float ct = fmaxf(mp - mn0p[j], 0.0f);
        x1c[j] = fmaxf(x0o[j] - ct, 0.0f);
    }
    if (!((unsigned)(R - 2) < HH)) {
        #pragma unroll
        for (int j = 0; j < 8; ++j) x1c[j] = INFINITY;
    }
    if (isL) { x1c[0] = INFINITY; x1c[1] = INFINITY; }
    if (isR) { x1c[6] = INFINITY; x1c[7] = INFINITY; }

    // rotate iter1 rings (coalesced in SSA)
    #pragma unroll
    for (int i = 0; i < 10; ++i) hm0o[i] = hm0c[i];
    #pragma unroll
    for (int j = 0; j < 8; ++j) { mn0p[j] = mn0n[j + 1]; hx0o[j] = hx0c[j]; x0o[j] = xA[j + 2]; }

    // ---- iter2 horizontal min, row R-2 ----
    float hm1c[6];
    #pragma unroll
    for (int k = 0; k < 6; ++k) hm1c[k] = min3f(x1c[k], x1c[k + 1], x1c[k + 2]);

    // ---- iter2 min-pool row R-3 ----
    float mn1n[6];
    #pragma unroll
    for (int k = 0; k < 6; ++k) mn1n[k] = min3f(hm1o[k], hm1n[k], hm1c[k]);
    if (!((unsigned)(R - 3) < HH)) {
        #pragma unroll
        for (int k = 0; k < 6; ++k) mn1n[k] = -INFINITY;
    }
    if (isL) mn1n[0] = -INFINITY;
    if (isR) mn1n[5] = -INFINITY;

    // ---- horiz max of mn1 row R-3 ----
    float hx1c[4];
    #pragma unroll
    for (int m = 0; m < 4; ++m) hx1c[m] = max3f(mn1n[m], mn1n[m + 1], mn1n[m + 2]);

    // ---- iter2 update: out row R-4 (wave-uniform branch) ----
    if (doStore) {
        float o[4];
        #pragma unroll
        for (int m = 0; m < 4; ++m) {
            float mp = max3f(hx1o[m], hx1n[m], hx1c[m]);
            float ct = fmaxf(mp - mn1p[m], 0.0f);
            o[m] = fmaxf(x1o[m] - ct, 0.0f);
        }
        if (FUSED) {
            acc0 += o[0] * cmpCur.x + o[1] * cmpCur.y + o[2] * cmpCur.z + o[3] * cmpCur.w;
            acc1 += o[0] + o[1] + o[2] + o[3];
        } else {
            ushort4 ov;
            ov.x = f2bf(o[0]); ov.y = f2bf(o[1]); ov.z = f2bf(o[2]); ov.w = f2bf(o[3]);
            *(ushort4*)(outp + (size_t)(R - 4) * WW + gx0) = ov;
        }
    }

    // rotate iter2 rings
    #pragma unroll
    for (int k = 0; k < 6; ++k) hm1o[k] = hm1c[k];
    #pragma unroll
    for (int m = 0; m < 4; ++m) { mn1p[m] = mn1n[m + 1]; hx1o[m] = hx1c[m]; x1o[m] = x1c[m + 2]; }
}

// Two fused soft-skeletonize iterations (T=2), bf16 intermediates, no LDS.
// Round-11 lesson: L3-warm replays run at identical speed -> NOT traffic
// bound; VALUBusy 47% at 2 waves/SIMD with only ~13us of VALU work in a
// 44us pass -> front-end (I$) streaming suspected: the 40-row full unroll
// is ~65-85KB of code vs 32KB I$. Fix: 4-row loop body (ring roles rotated
// manually -> zero cross-iteration movs), rolled x10 -> ~6-8KB hot loop,
// I$-resident. Masks become wave-uniform runtime branches; loads always-on
// clamped.
template <int SRCF32, int FUSED>
__global__ __launch_bounds__(256) void skel2b_t(const float* __restrict__ sfA,
                                                const float* __restrict__ sfB,
                                                const unsigned short* __restrict__ shA,
                                                const unsigned short* __restrict__ shB,
                                                const float* __restrict__ cmpA,
                                                const float* __restrict__ cmpB,
                                                unsigned short* __restrict__ dst,
                                                float* __restrict__ partials) {
    const int s = blockIdx.x * 64 + threadIdx.x;            // span 0..127
    const int y0 = (blockIdx.y * 4 + threadIdx.y) * CHUNK;  // output row start
    const int z = blockIdx.z;
    const float* imgF = nullptr;
    const unsigned short* imgH = nullptr;
    if (SRCF32) imgF = (z < BB) ? (sfA + (size_t)z * (HH * WW))
                                : (sfB + (size_t)(z - BB) * (HH * WW));
    else        imgH = (z < BB) ? (shA + (size_t)z * (HH * WW))
                                : (shB + (size_t)(z - BB) * (HH * WW));
    const float* cmp = nullptr;
    if (FUSED) cmp = (z < BB) ? (cmpA + (size_t)z * (HH * WW))
                              : (cmpB + (size_t)(z - BB) * (HH * WW));
    unsigned short* outp = FUSED ? nullptr : (dst + (size_t)z * (HH * WW));
    const int gx0 = 4 * s;
    const bool isL = (s == 0), isR = (s == 127);
    const int cm4 = isL ? 0 : gx0 - 4;
    const int cp4 = isR ? gx0 : gx0 + 4;

    // persistent ring state
    float hm0a[10], hm0b[10], mn0p[8];
    float hx0a[8], hx0b[8], x0a[8], x0b[8];
    float hm1a[6], hm1b[6], mn1p[4];
    float hx1a[4], hx1b[4], x1a[4], x1b[4];
    float xs0[12], xs1[12], xs2[12], xs3[12];
    float4 cq0, cq1, cq2, cq3;

    #pragma unroll
    for (int i = 0; i < 10; ++i) { hm0a[i] = INFINITY; hm0b[i] = INFINITY; }
    #pragma unroll
    for (int j = 0; j < 8; ++j)  { mn0p[j] = -INFINITY; hx0a[j] = -INFINITY; hx0b[j] = -INFINITY; x0a[j] = INFINITY; x0b[j] = INFINITY; }
    #pragma unroll
    for (int k = 0; k < 6; ++k)  { hm1a[k] = INFINITY; hm1b[k] = INFINITY; }
    #pragma unroll
    for (int m = 0; m < 4; ++m)  { mn1p[m] = -INFINITY; hx1a[m] = -INFINITY; hx1b[m] = -INFINITY; x1a[m] = INFINITY; x1b[m] = INFINITY; }
    cq0.x = cq0.y = cq0.z = cq0.w = 0.f;
    cq1 = cq0; cq2 = cq0; cq3 = cq0;

    float acc0 = 0.0f, acc1 = 0.0f;

    // prefetch rows y0-4 .. y0-2 into slots 0..2 (slot 3 loaded at step 0)
    loadrow12<SRCF32>(imgF, imgH, y0 - 4, cm4, gx0, cp4, isL, isR, xs0);
    loadrow12<SRCF32>(imgF, imgH, y0 - 3, cm4, gx0, cp4, isL, isR, xs1);
    loadrow12<SRCF32>(imgF, imgH, y0 - 2, cm4, gx0, cp4, isL, isR, xs2);

    #pragma unroll 1
    for (int it = 0; it < (CHUNK + 8) / 4; ++it) {
        const int Rb = y0 - 4 + 4 * it;
        const bool doStore = (it >= 2);
        rowstep<SRCF32, FUSED>(imgF, imgH, cmp, outp, acc0, acc1,
            Rb + 0, cm4, gx0, cp4, isL, isR, doStore,
            xs0, xs3, hm0a, hm0b, mn0p, hx0a, hx0b, x0a, x0b,
            hm1a, hm1b, mn1p, hx1a, hx1b, x1a, x1b, cq0, cq3);
        rowstep<SRCF32, FUSED>(imgF, imgH, cmp, outp, acc0, acc1,
            Rb + 1, cm4, gx0, cp4, isL, isR, doStore,
            xs1, xs0, hm0b, hm0a, mn0p, hx0b, hx0a, x0b, x0a,
            hm1b, hm1a, mn1p, hx1b, hx1a, x1b, x1a, cq1, cq0);
        rowstep<SRCF32, FUSED>(imgF, imgH, cmp, outp, acc0, acc1,
            Rb + 2, cm4, gx0, cp4, isL, isR, doStore,
            xs2, xs1, hm0a, hm0b, mn0p, hx0a, hx0b, x0a, x0b,
            hm1a, hm1b, mn1p, hx1a, hx1b, x1a, x1b, cq2, cq1);
        rowstep<SRCF32, FUSED>(imgF, imgH, cmp, outp, acc0, acc1,
            Rb + 3, cm4, gx0, cp4, isL, isR, doStore,
            xs3, xs2, hm0b, hm0a, mn0p, hx0b, hx0a, x0b, x0a,
            hm1b, hm1a, mn1p, hx1b, hx1a, x1b, x1a, cq3, cq2);
    }

    if (FUSED) {
        for (int off = 32; off; off >>= 1) {
            acc0 += __shfl_down(acc0, off);
            acc1 += __shfl_down(acc1, off);
        }
        __shared__ float red[4][2];
        if (threadIdx.x == 0) { red[threadIdx.y][0] = acc0; red[threadIdx.y][1] = acc1; }
        __syncthreads();
        if (threadIdx.x == 0 && threadIdx.y == 0) {
            const int tile = blockIdx.x * gridDim.y + blockIdx.y;  // 0..7
            float* p = partials + ((size_t)z * 16 + tile) * 2;
            p[0] = red[0][0] + red[1][0] + red[2][0] + red[3][0];
            p[1] = red[0][1] + red[1][1] + red[2][1] + red[3][1];
        }
    }
}

// partials layout: [z][16 tile slots][2] (first ntiles used per z);
// z<32: (sum clp*tgt, sum clp); z>=32: (sum skt*prd, sum skt)
__global__ __launch_bounds__(64) void finalize2(const float* __restrict__ partials,
                                                int ntiles,
                                                float* __restrict__ out) {
    const int b = threadIdx.x;
    float iflat = 0.f, tflat = 0.f;
    if (b < BB) {
        float v0 = 0.f, v1 = 0.f, v2 = 0.f, v3 = 0.f;
        for (int t = 0; t < ntiles; ++t) {
            v0 += partials[((size_t)b * 16 + t) * 2 + 0];
            v1 += partials[((size_t)b * 16 + t) * 2 + 1];
            v2 += partials[((size_t)(b + BB) * 16 + t) * 2 + 0];
            v3 += partials[((size_t)(b + BB) * 16 + t) * 2 + 1];
        }
        iflat = (v0 + 1e-6f) / (v1 + 1e-6f);
        tflat = (v2 + 1e-6f) / (v3 + 1e-6f);
    }
    float prod = iflat * tflat;
    float ssum = iflat + tflat;
    for (int off = 32; off; off >>= 1) {
        prod += __shfl_down(prod, off);
        ssum += __shfl_down(ssum, off);
    }
    if (threadIdx.x == 0) out[0] = 1.0f - 2.0f * prod / ssum;
}

extern "C" void kernel_launch(void* const* d_in, const int* in_sizes, int n_in,
                              void* d_out, int out_size, void* d_ws, size_t ws_size,
                              hipStream_t stream) {
    const float* pred = (const float*)d_in[0];
    const float* target = (const float*)d_in[1];
    float* out = (float*)d_out;
    char* ws = (char*)d_ws;
    const size_t N = (size_t)HH * WW;
    const size_t HALF = (size_t)BB * N;                 // elements per 32-image half
    const size_t IMG16 = HALF * sizeof(unsigned short); // 16 MB (bf16, 32 imgs)

    dim3 block(64, 4);
    const int nby = HH / (CHUNK * 4);                   // 4
    const int ntiles = 2 * nby;                         // 8

    if (ws_size >= 4 * IMG16 + (1 << 16)) {
        // z=64 path: both chains per dispatch; bf16 ping-pong A<->B (32MB each)
        unsigned short* A = (unsigned short*)ws;
        unsigned short* B = (unsigned short*)(ws + 2 * IMG16);
        float* partials = (float*)(ws + 4 * IMG16);     // 64*16*2 floats
        dim3 grid(2, nby, 2 * BB);
        skel2b_t<1, 0><<<grid, block, 0, stream>>>(pred, target, nullptr, nullptr,
                                                   nullptr, nullptr, A, nullptr);
        skel2b_t<0, 0><<<grid, block, 0, stream>>>(nullptr, nullptr, A, A + HALF,
                                                   nullptr, nullptr, B, nullptr);
        skel2b_t<0, 0><<<grid, block, 0, stream>>>(nullptr, nullptr, B, B + HALF,
                                                   nullptr, nullptr, A, nullptr);
        skel2b_t<0, 0><<<grid, block, 0, stream>>>(nullptr, nullptr, A, A + HALF,
                                                   nullptr, nullptr, B, nullptr);
        // final pass fused with reduction: z<32 companion=target, z>=32 companion=pred
        skel2b_t<0, 1><<<grid, block, 0, stream>>>(nullptr, nullptr, B, B + HALF,
                                                   target, pred, nullptr, partials);
        finalize2<<<1, 64, 0, stream>>>(partials, ntiles, out);
    } else {
        // fallback: z=32 path with 2x16MB bf16 buffers, per-chain passes
        unsigned short* b0 = (unsigned short*)ws;
        unsigned short* b1 = (unsigned short*)(ws + IMG16);
        float* partials = (float*)(ws + 2 * IMG16);
        dim3 grid(2, nby, BB);
        // pred chain
        skel2b_t<1, 0><<<grid, block, 0, stream>>>(pred, pred, nullptr, nullptr,
                                                   nullptr, nullptr, b0, nullptr);
        skel2b_t<0, 0><<<grid, block, 0, stream>>>(nullptr, nullptr, b0, b0,
                                                   nullptr, nullptr, b1, nullptr);
        skel2b_t<0, 0><<<grid, block, 0, stream>>>(nullptr, nullptr, b1, b1,
                                                   nullptr, nullptr, b0, nullptr);
        skel2b_t<0, 0><<<grid, block, 0, stream>>>(nullptr, nullptr, b0, b0,
                                                   nullptr, nullptr, b1, nullptr);
        skel2b_t<0, 1><<<grid, block, 0, stream>>>(nullptr, nullptr, b1, b1,
                                                   target, target, nullptr, partials);
        // target chain
        skel2b_t<1, 0><<<grid, block, 0, stream>>>(target, target, nullptr, nullptr,
                                                   nullptr, nullptr, b0, nullptr);
        skel2b_t<0, 0><<<grid, block, 0, stream>>>(nullptr, nullptr, b0, b0,
                                                   nullptr, nullptr, b1, nullptr);
        skel2b_t<0, 0><<<grid, block, 0, stream>>>(nullptr, nullptr, b1, b1,
                                                   nullptr, nullptr, b0, nullptr);
        skel2b_t<0, 0><<<grid, block, 0, stream>>>(nullptr, nullptr, b0, b0,
                                                   nullptr, nullptr, b1, nullptr);
        skel2b_t<0, 1><<<grid, block, 0, stream>>>(nullptr, nullptr, b1, b1,
                                                   pred, pred, nullptr,
                                                   partials + (size_t)BB * 16 * 2);
        finalize2<<<1, 64, 0, stream>>>(partials, ntiles, out);
    }
}